// Round 6
// baseline (266.878 us; speedup 1.0000x reference)
//
#include <hip/hip_runtime.h>
#include <cstdint>
#include <cstddef>

typedef __attribute__((ext_vector_type(8))) short bf16x8;
typedef __attribute__((ext_vector_type(4))) float f32x4;
typedef __attribute__((ext_vector_type(4))) unsigned short u16x4;

#define AS1 __attribute__((address_space(1)))
#define AS3 __attribute__((address_space(3)))

__device__ __forceinline__ unsigned short f2bf(float f) {
  union { float f; unsigned int u; } v; v.f = f;
  unsigned int r = v.u + 0x7fffu + ((v.u >> 16) & 1u);
  return (unsigned short)(r >> 16);
}

__device__ __forceinline__ void gll16(const unsigned short* g, unsigned short* l) {
  __builtin_amdgcn_global_load_lds((const AS1 void*)g, (AS3 void*)l, 16, 0, 0);
}

// ---------------- x convert ----------------
__global__ __launch_bounds__(256) void cvt_bf16_kernel(const float* __restrict__ src,
                                                       unsigned short* __restrict__ dst, int n) {
  int idx = (blockIdx.x * blockDim.x + threadIdx.x) * 4;
  if (idx >= n) return;
  const float* s = src + idx;
  u16x4 o = { f2bf(s[0]), f2bf(s[1]), f2bf(s[2]), f2bf(s[3]) };
  *(u16x4*)(dst + idx) = o;
}

// ---------------- ALL weight transposes in one dispatch ----------------
__global__ __launch_bounds__(256) void transpose_cvt_all(
    const float* __restrict__ Wg, const float* __restrict__ Wu,
    const float* __restrict__ Wd, const float* __restrict__ Sg,
    const float* __restrict__ Su, const float* __restrict__ Sd,
    unsigned short* __restrict__ WguT, unsigned short* __restrict__ WdT,
    unsigned short* __restrict__ SguT, unsigned short* __restrict__ SdT) {
  const int z = blockIdx.z;
  const float* src; unsigned short* dst; int R, C, drp;
  if (z < 8)       { src = Wg + (size_t)z * 524288; dst = WguT + (size_t)z * 1048576; R = 1024; C = 512; drp = 2048; }
  else if (z < 16) { src = Wu + (size_t)(z - 8) * 524288; dst = WguT + (size_t)(z - 8) * 1048576 + 1024; R = 1024; C = 512; drp = 2048; }
  else if (z < 24) { src = Wd + (size_t)(z - 16) * 524288; dst = WdT + (size_t)(z - 16) * 524288; R = 512; C = 1024; drp = 512; }
  else if (z == 24){ src = Sg; dst = SguT; R = 1024; C = 1024; drp = 2048; }
  else if (z == 25){ src = Su; dst = SguT + 1024; R = 1024; C = 1024; drp = 2048; }
  else             { src = Sd; dst = SdT; R = 1024; C = 1024; drp = 1024; }
  const int c0 = blockIdx.x * 64, r0 = blockIdx.y * 64;
  if (c0 >= C || r0 >= R) return;
  __shared__ float tile[64][65];
  const int tc = threadIdx.x & 63, tr = threadIdx.x >> 6;
#pragma unroll
  for (int i = 0; i < 16; i++) {
    int r = tr + i * 4;
    tile[r][tc] = src[(size_t)(r0 + r) * C + c0 + tc];
  }
  __syncthreads();
#pragma unroll
  for (int i = 0; i < 16; i++) {
    int cc = tr + i * 4;
    dst[(size_t)(c0 + cc) * drp + (r0 + tc)] = f2bf(tile[tc][cc]);
  }
}

// ---------------- router: logits ----------------
__global__ __launch_bounds__(256) void logits_kernel(const float* __restrict__ x,
                                                     const float* __restrict__ Wr,
                                                     float* __restrict__ logits) {
  const int t = blockIdx.x * 4 + (threadIdx.x >> 6);
  const int lane = threadIdx.x & 63;
  const float* xr = x + (size_t)t * 1024;
  float acc[8];
#pragma unroll
  for (int e = 0; e < 8; e++) acc[e] = 0.f;
#pragma unroll
  for (int i = 0; i < 16; i++) {
    int d = lane + i * 64;
    float xv = xr[d];
    const float4* w = (const float4*)(Wr + d * 8);
    float4 w0 = w[0], w1 = w[1];
    acc[0] += xv * w0.x; acc[1] += xv * w0.y; acc[2] += xv * w0.z; acc[3] += xv * w0.w;
    acc[4] += xv * w1.x; acc[5] += xv * w1.y; acc[6] += xv * w1.z; acc[7] += xv * w1.w;
  }
#pragma unroll
  for (int off = 32; off > 0; off >>= 1)
#pragma unroll
    for (int e = 0; e < 8; e++) acc[e] += __shfl_down(acc[e], off);
  if (lane == 0) {
#pragma unroll
    for (int e = 0; e < 8; e++) logits[t * 8 + e] = acc[e];
  }
}

// ---------------- router: assignment ----------------
__global__ __launch_bounds__(1024) void assign_kernel(
    const float* __restrict__ logits, const float* __restrict__ bias,
    int* __restrict__ list, int* __restrict__ ridx, float* __restrict__ rp,
    int* __restrict__ counts_g, int* __restrict__ offs_g) {
  __shared__ int cnt[8];
  __shared__ int offs[9];
  const int tid = threadIdx.x;
  if (tid < 8) cnt[tid] = 0;
  __syncthreads();
  int te[2][2], tpos[2][2];
  float tp[2][2];
#pragma unroll
  for (int it = 0; it < 2; it++) {
    int t = tid + it * 1024;
    float v[8];
#pragma unroll
    for (int e = 0; e < 8; e++) v[e] = logits[t * 8 + e] + bias[e];
    int i0 = 0;
#pragma unroll
    for (int e = 1; e < 8; e++) if (v[e] > v[i0]) i0 = e;
    int i1 = (i0 == 0) ? 1 : 0;
#pragma unroll
    for (int e = 0; e < 8; e++) if (e != i0 && v[e] > v[i1]) i1 = e;
    float pa = 1.f / (1.f + __expf(v[i1] - v[i0]));
    te[it][0] = i0; te[it][1] = i1;
    tp[it][0] = pa; tp[it][1] = 1.f - pa;
    tpos[it][0] = atomicAdd(&cnt[i0], 1);
    tpos[it][1] = atomicAdd(&cnt[i1], 1);
  }
  __syncthreads();
  if (tid == 0) {
    int s = 0;
#pragma unroll
    for (int e = 0; e < 8; e++) { offs[e] = s; s += cnt[e]; }
    offs[8] = s;
#pragma unroll
    for (int e = 0; e < 8; e++) { counts_g[e] = cnt[e]; offs_g[e] = offs[e]; }
    offs_g[8] = s;
  }
  __syncthreads();
#pragma unroll
  for (int it = 0; it < 2; it++) {
    int t = tid + it * 1024;
#pragma unroll
    for (int k = 0; k < 2; k++) {
      int grow = offs[te[it][k]] + tpos[it][k];
      list[grow] = t;
      ridx[t * 2 + k] = grow;
      rp[t * 2 + k] = tp[it][k];
    }
  }
}

// ---------------- fused TN GEMM: 64x256 tile, 256 thr (4 waves, 64x64/wave), dbuf ----------------
// 1-D grid, XCD-pinned: routed blocks have blockIdx%8 == expert, so each expert's
// B slab (2 MB) stays in its XCD's 4 MB L2 across the block's M-loop.
// MODE 0 gate|up: routed b<256: e=b&7, s=b>>3, n0=(s&3)*256, mslot=s>>2 (step 8).
//                 shared b in [256,512): n0=(b'&7)*256, m=b'>>3 (step 32).
// MODE 1 down:    routed b<256: same but K=512, N=1024. shared b in [256,384): n0=(b'&3)*256, m=b'>>2.
template <int MODE>
__global__ __launch_bounds__(256, 2) void gemm_tn_kernel(
    const unsigned short* __restrict__ Xb, const unsigned short* __restrict__ He,
    const unsigned short* __restrict__ Hs, const unsigned short* __restrict__ Wgu,
    const unsigned short* __restrict__ Sgu, const unsigned short* __restrict__ Wd,
    const unsigned short* __restrict__ Sd, unsigned short* __restrict__ HeOut,
    unsigned short* __restrict__ HsOut, float* __restrict__ De, float* __restrict__ Ds,
    const int* __restrict__ list, const int* __restrict__ counts,
    const int* __restrict__ offs) {
  const int b = blockIdx.x;
  const bool routed = (b < 256);
  int cnt, lda, K, n0, mslot, mstep, ldh = 0;
  const unsigned short* A;
  const unsigned short* B;
  const int* alist = nullptr;
  unsigned short* H = nullptr;
  float* D = nullptr;

  if (routed) {
    const int e = b & 7;
    const int s = b >> 3;
    n0 = (s & 3) * 256; mslot = s >> 2; mstep = 8;
    cnt = counts[e];
    if (MODE == 0) {
      A = Xb; alist = list + offs[e]; lda = 1024; K = 1024;
      B = Wgu + (size_t)e * 1048576; H = HeOut + (size_t)offs[e] * 512; ldh = 512;
    } else {
      A = He + (size_t)offs[e] * 512; lda = 512; K = 512;
      B = Wd + (size_t)e * 524288; D = De + (size_t)offs[e] * 1024;
    }
  } else {
    const int s = b - 256;
    cnt = 2048; mstep = 32;
    if (MODE == 0) {
      n0 = (s & 7) * 256; mslot = s >> 3;
      A = Xb; lda = 1024; K = 1024; B = Sgu; H = HsOut; ldh = 1024;
    } else {
      n0 = (s & 3) * 256; mslot = s >> 2;
      A = Hs; lda = 1024; K = 1024; B = Sd; D = Ds;
    }
  }

  __shared__ unsigned short Asb[2][64 * 32];     // 2 x 4 KB
  __shared__ unsigned short Bsb[2][256 * 32];    // 2 x 16 KB

  const int tid = threadIdx.x;
  const int lane = tid & 63;
  const int wv = tid >> 6;               // 0..3
  const int lrow = lane >> 2;            // 0..15
  const int lcol = (lane & 3) * 8;

  // B staging: wave wv owns Bs rows [wv*64, wv*64+64), 4 chunks of 16 rows
  const unsigned short* bsrc[4];
#pragma unroll
  for (int g = 0; g < 4; g++)
    bsrc[g] = B + (size_t)(n0 + wv * 64 + g * 16 + lrow) * K + lcol;

  const int fl = lane & 15;
  const int q = lane >> 4;
  const int wn = wv * 64;                // wave's column base within 256-tile

  for (int mi = mslot; mi * 64 < cnt; mi += mstep) {
    const int m0 = mi * 64;
    // A staging: wave wv owns As rows [wv*16, wv*16+16)
    int r = m0 + wv * 16 + lrow; if (r >= cnt) r = cnt - 1;
    const unsigned short* asrc =
        A + (size_t)((MODE == 0 && routed) ? alist[r] : r) * lda + lcol;

    f32x4 acc[4][4];
    f32x4 zero = {0.f, 0.f, 0.f, 0.f};
#pragma unroll
    for (int i = 0; i < 4; i++)
#pragma unroll
      for (int j = 0; j < 4; j++) acc[i][j] = zero;

    // prologue into buf 0 (previous m-tile's last compute used buf 1 — even iter counts)
    gll16(asrc, &Asb[0][wv * 512]);
#pragma unroll
    for (int g = 0; g < 4; g++) gll16(bsrc[g], &Bsb[0][(wv * 64 + g * 16) * 32]);

    int cur = 0;
    for (int k0 = 0; k0 < K; k0 += 32) {
      __syncthreads();     // drains loads issued last iter (one MFMA-stage of slack)
      if (k0 + 32 < K) {
        const int nb = cur ^ 1;
        gll16(asrc + k0 + 32, &Asb[nb][wv * 512]);
#pragma unroll
        for (int g = 0; g < 4; g++) gll16(bsrc[g] + k0 + 32, &Bsb[nb][(wv * 64 + g * 16) * 32]);
      }
      bf16x8 af[4], bfr[4];
#pragma unroll
      for (int i = 0; i < 4; i++) af[i] = *(const bf16x8*)(&Asb[cur][(i * 16 + fl) * 32 + q * 8]);
#pragma unroll
      for (int j = 0; j < 4; j++) bfr[j] = *(const bf16x8*)(&Bsb[cur][(wn + j * 16 + fl) * 32 + q * 8]);
#pragma unroll
      for (int i = 0; i < 4; i++)
#pragma unroll
        for (int j = 0; j < 4; j++)
          acc[i][j] = __builtin_amdgcn_mfma_f32_16x16x32_bf16(af[i], bfr[j], acc[i][j], 0, 0, 0);
      cur ^= 1;
    }

    if (MODE == 0) {
#pragma unroll
      for (int i = 0; i < 4; i++) {
#pragma unroll
        for (int j = 0; j < 4; j++) {
#pragma unroll
          for (int r2 = 0; r2 < 4; r2++) {
            int grow = m0 + i * 16 + q * 4 + r2;
            float v = acc[i][j][r2];
            float pv = __shfl_xor(v, 1);
            if ((lane & 1) == 0 && grow < cnt) {
              float s = v / (1.f + __expf(-v));
              int colh = (n0 + wn + j * 16 + fl) >> 1;
              H[(size_t)grow * ldh + colh] = f2bf(s * pv);
            }
          }
        }
      }
    } else {
#pragma unroll
      for (int i = 0; i < 4; i++) {
#pragma unroll
        for (int r2 = 0; r2 < 4; r2++) {
          int grow = m0 + i * 16 + q * 4 + r2;
          if (grow >= cnt) continue;
#pragma unroll
          for (int j = 0; j < 4; j++) {
            int col = n0 + wn + j * 16 + fl;
            D[(size_t)grow * 1024 + col] = acc[i][j][r2];
          }
        }
      }
    }
  }
}

// ---------------- combine ----------------
__global__ __launch_bounds__(256) void combine_kernel(
    const float* __restrict__ Ds, const float* __restrict__ De,
    const int* __restrict__ ridx, const float* __restrict__ rp,
    float* __restrict__ out) {
  const int t = blockIdx.x;
  const int i0 = ridx[t * 2], i1 = ridx[t * 2 + 1];
  const float p0 = rp[t * 2], p1 = rp[t * 2 + 1];
  const float4* a  = (const float4*)(Ds + (size_t)t * 1024);
  const float4* b0 = (const float4*)(De + (size_t)i0 * 1024);
  const float4* b1 = (const float4*)(De + (size_t)i1 * 1024);
  float4* o = (float4*)(out + (size_t)t * 1024);
  int c = threadIdx.x;
  float4 va = a[c], v0 = b0[c], v1 = b1[c];
  float4 r;
  r.x = va.x + p0 * v0.x + p1 * v1.x;
  r.y = va.y + p0 * v0.y + p1 * v1.y;
  r.z = va.z + p0 * v0.z + p1 * v1.z;
  r.w = va.w + p0 * v0.w + p1 * v1.w;
  o[c] = r;
}

// ---------------- launch ----------------
extern "C" void kernel_launch(void* const* d_in, const int* in_sizes, int n_in,
                              void* d_out, int out_size, void* d_ws, size_t ws_size,
                              hipStream_t stream) {
  const float* x    = (const float*)d_in[0];
  const float* Wr   = (const float*)d_in[1];
  const float* Wg   = (const float*)d_in[2];
  const float* Wu   = (const float*)d_in[3];
  const float* Wd   = (const float*)d_in[4];
  const float* Sg   = (const float*)d_in[5];
  const float* Su   = (const float*)d_in[6];
  const float* Sd   = (const float*)d_in[7];
  const float* bias = (const float*)d_in[8];
  float* out = (float*)d_out;

  char* ws = (char*)d_ws;
  size_t o = 0;
  auto alloc = [&](size_t b) { char* p = ws + o; o += (b + 255) & ~(size_t)255; return p; };
  unsigned short* Xb   = (unsigned short*)alloc((size_t)2048 * 1024 * 2);
  unsigned short* WguT = (unsigned short*)alloc((size_t)8 * 1024 * 1024 * 2);
  unsigned short* WdT  = (unsigned short*)alloc((size_t)8 * 1024 * 512 * 2);
  unsigned short* SguT = (unsigned short*)alloc((size_t)2048 * 1024 * 2);
  unsigned short* SdT  = (unsigned short*)alloc((size_t)1024 * 1024 * 2);
  float* logits = (float*)alloc((size_t)2048 * 8 * 4);
  int*   list   = (int*)alloc((size_t)4096 * 4);
  int*   ridx   = (int*)alloc((size_t)2048 * 2 * 4);
  float* rp     = (float*)alloc((size_t)2048 * 2 * 4);
  int*   counts = (int*)alloc(64);
  int*   offs   = (int*)alloc(64);
  unsigned short* He = (unsigned short*)alloc((size_t)4096 * 512 * 2);
  unsigned short* Hs = (unsigned short*)alloc((size_t)2048 * 1024 * 2);
  float* De = (float*)alloc((size_t)4096 * 1024 * 4);
  float* Ds = (float*)alloc((size_t)2048 * 1024 * 4);

  cvt_bf16_kernel<<<2048, 256, 0, stream>>>(x, Xb, 2048 * 1024);
  transpose_cvt_all<<<dim3(16, 16, 27), 256, 0, stream>>>(Wg, Wu, Wd, Sg, Su, Sd,
                                                          WguT, WdT, SguT, SdT);

  logits_kernel<<<512, 256, 0, stream>>>(x, Wr, logits);
  assign_kernel<<<1, 1024, 0, stream>>>(logits, bias, list, ridx, rp, counts, offs);

  gemm_tn_kernel<0><<<512, 256, 0, stream>>>(
      Xb, He, Hs, WguT, SguT, WdT, SdT, He, Hs, De, Ds, list, counts, offs);
  gemm_tn_kernel<1><<<384, 256, 0, stream>>>(
      Xb, He, Hs, WguT, SguT, WdT, SdT, He, Hs, De, Ds, list, counts, offs);

  combine_kernel<<<2048, 256, 0, stream>>>(Ds, De, ridx, rp, out);
}

// Round 8
// 239.254 us; speedup vs baseline: 1.1155x; 1.1155x over previous
//
#include <hip/hip_runtime.h>
#include <cstdint>
#include <cstddef>

typedef __attribute__((ext_vector_type(8))) short bf16x8;
typedef __attribute__((ext_vector_type(4))) float f32x4;
typedef __attribute__((ext_vector_type(4))) unsigned short u16x4;

#define AS1 __attribute__((address_space(1)))
#define AS3 __attribute__((address_space(3)))

__device__ __forceinline__ unsigned short f2bf(float f) {
  union { float f; unsigned int u; } v; v.f = f;
  unsigned int r = v.u + 0x7fffu + ((v.u >> 16) & 1u);
  return (unsigned short)(r >> 16);
}

__device__ __forceinline__ void gll16(const unsigned short* g, unsigned short* l) {
  __builtin_amdgcn_global_load_lds((const AS1 void*)g, (AS3 void*)l, 16, 0, 0);
}

// ---------------- x convert ----------------
__global__ __launch_bounds__(256) void cvt_bf16_kernel(const float* __restrict__ src,
                                                       unsigned short* __restrict__ dst, int n) {
  int idx = (blockIdx.x * blockDim.x + threadIdx.x) * 4;
  if (idx >= n) return;
  const float* s = src + idx;
  u16x4 o = { f2bf(s[0]), f2bf(s[1]), f2bf(s[2]), f2bf(s[3]) };
  *(u16x4*)(dst + idx) = o;
}

// ---------------- ALL weight transposes in one dispatch ----------------
__global__ __launch_bounds__(256) void transpose_cvt_all(
    const float* __restrict__ Wg, const float* __restrict__ Wu,
    const float* __restrict__ Wd, const float* __restrict__ Sg,
    const float* __restrict__ Su, const float* __restrict__ Sd,
    unsigned short* __restrict__ WguT, unsigned short* __restrict__ WdT,
    unsigned short* __restrict__ SguT, unsigned short* __restrict__ SdT) {
  const int z = blockIdx.z;
  const float* src; unsigned short* dst; int R, C, drp;
  if (z < 8)       { src = Wg + (size_t)z * 524288; dst = WguT + (size_t)z * 1048576; R = 1024; C = 512; drp = 2048; }
  else if (z < 16) { src = Wu + (size_t)(z - 8) * 524288; dst = WguT + (size_t)(z - 8) * 1048576 + 1024; R = 1024; C = 512; drp = 2048; }
  else if (z < 24) { src = Wd + (size_t)(z - 16) * 524288; dst = WdT + (size_t)(z - 16) * 524288; R = 512; C = 1024; drp = 512; }
  else if (z == 24){ src = Sg; dst = SguT; R = 1024; C = 1024; drp = 2048; }
  else if (z == 25){ src = Su; dst = SguT + 1024; R = 1024; C = 1024; drp = 2048; }
  else             { src = Sd; dst = SdT; R = 1024; C = 1024; drp = 1024; }
  const int c0 = blockIdx.x * 64, r0 = blockIdx.y * 64;
  if (c0 >= C || r0 >= R) return;
  __shared__ float tile[64][65];
  const int tc = threadIdx.x & 63, tr = threadIdx.x >> 6;
#pragma unroll
  for (int i = 0; i < 16; i++) {
    int r = tr + i * 4;
    tile[r][tc] = src[(size_t)(r0 + r) * C + c0 + tc];
  }
  __syncthreads();
#pragma unroll
  for (int i = 0; i < 16; i++) {
    int cc = tr + i * 4;
    dst[(size_t)(c0 + cc) * drp + (r0 + tc)] = f2bf(tile[tc][cc]);
  }
}

// ---------------- router: logits ----------------
__global__ __launch_bounds__(256) void logits_kernel(const float* __restrict__ x,
                                                     const float* __restrict__ Wr,
                                                     float* __restrict__ logits) {
  const int t = blockIdx.x * 4 + (threadIdx.x >> 6);
  const int lane = threadIdx.x & 63;
  const float* xr = x + (size_t)t * 1024;
  float acc[8];
#pragma unroll
  for (int e = 0; e < 8; e++) acc[e] = 0.f;
#pragma unroll
  for (int i = 0; i < 16; i++) {
    int d = lane + i * 64;
    float xv = xr[d];
    const float4* w = (const float4*)(Wr + d * 8);
    float4 w0 = w[0], w1 = w[1];
    acc[0] += xv * w0.x; acc[1] += xv * w0.y; acc[2] += xv * w0.z; acc[3] += xv * w0.w;
    acc[4] += xv * w1.x; acc[5] += xv * w1.y; acc[6] += xv * w1.z; acc[7] += xv * w1.w;
  }
#pragma unroll
  for (int off = 32; off > 0; off >>= 1)
#pragma unroll
    for (int e = 0; e < 8; e++) acc[e] += __shfl_down(acc[e], off);
  if (lane == 0) {
#pragma unroll
    for (int e = 0; e < 8; e++) logits[t * 8 + e] = acc[e];
  }
}

// ---------------- router: assignment ----------------
__global__ __launch_bounds__(1024) void assign_kernel(
    const float* __restrict__ logits, const float* __restrict__ bias,
    int* __restrict__ list, int* __restrict__ ridx, float* __restrict__ rp,
    int* __restrict__ counts_g, int* __restrict__ offs_g) {
  __shared__ int cnt[8];
  __shared__ int offs[9];
  const int tid = threadIdx.x;
  if (tid < 8) cnt[tid] = 0;
  __syncthreads();
  int te[2][2], tpos[2][2];
  float tp[2][2];
#pragma unroll
  for (int it = 0; it < 2; it++) {
    int t = tid + it * 1024;
    float v[8];
#pragma unroll
    for (int e = 0; e < 8; e++) v[e] = logits[t * 8 + e] + bias[e];
    int i0 = 0;
#pragma unroll
    for (int e = 1; e < 8; e++) if (v[e] > v[i0]) i0 = e;
    int i1 = (i0 == 0) ? 1 : 0;
#pragma unroll
    for (int e = 0; e < 8; e++) if (e != i0 && v[e] > v[i1]) i1 = e;
    float pa = 1.f / (1.f + __expf(v[i1] - v[i0]));
    te[it][0] = i0; te[it][1] = i1;
    tp[it][0] = pa; tp[it][1] = 1.f - pa;
    tpos[it][0] = atomicAdd(&cnt[i0], 1);
    tpos[it][1] = atomicAdd(&cnt[i1], 1);
  }
  __syncthreads();
  if (tid == 0) {
    int s = 0;
#pragma unroll
    for (int e = 0; e < 8; e++) { offs[e] = s; s += cnt[e]; }
    offs[8] = s;
#pragma unroll
    for (int e = 0; e < 8; e++) { counts_g[e] = cnt[e]; offs_g[e] = offs[e]; }
    offs_g[8] = s;
  }
  __syncthreads();
#pragma unroll
  for (int it = 0; it < 2; it++) {
    int t = tid + it * 1024;
#pragma unroll
    for (int k = 0; k < 2; k++) {
      int grow = offs[te[it][k]] + tpos[it][k];
      list[grow] = t;
      ridx[t * 2 + k] = grow;
      rp[t * 2 + k] = tp[it][k];
    }
  }
}

// ---------------- pipelined K-loop: NK compile-time, fully unrolled, 3 LDS buffers ----------------
// Buffer stride = 4096 elements (8 KB). K-tile global stride = 32 elements (64 B) -> imm offsets.
// Exactly 4 VMEM ops/tile in fixed order; vmcnt(4) completes the tile about to be read while
// keeping the next tile's 4 loads in flight across the raw s_barrier.
template <int NK>
__device__ __forceinline__ void kloop(
    const unsigned short* ga0, const unsigned short* ga1,
    const unsigned short* gb0, const unsigned short* gb1,
    unsigned short* lwA0, unsigned short* lwA1,
    unsigned short* lwB0, unsigned short* lwB1,
    const unsigned short* lrA, const unsigned short* lrB,
    f32x4 (&acc)[4][4]) {
  // prologue: tiles 0,1 -> buffers 0,1
  gll16(ga0, lwA0);          gll16(ga1, lwA1);
  gll16(gb0, lwB0);          gll16(gb1, lwB1);
  gll16(ga0 + 32, lwA0 + 4096); gll16(ga1 + 32, lwA1 + 4096);
  gll16(gb0 + 32, lwB0 + 4096); gll16(gb1 + 32, lwB1 + 4096);
#pragma unroll
  for (int i = 0; i < NK; ++i) {
    if (i + 1 < NK) asm volatile("s_waitcnt vmcnt(4) lgkmcnt(0)\n\ts_barrier" ::: "memory");
    else            asm volatile("s_waitcnt vmcnt(0) lgkmcnt(0)\n\ts_barrier" ::: "memory");
    if (i + 2 < NK) {
      const int bo = ((i + 2) % 3) * 4096;
      const int ko = (i + 2) * 32;
      gll16(ga0 + ko, lwA0 + bo); gll16(ga1 + ko, lwA1 + bo);
      gll16(gb0 + ko, lwB0 + bo); gll16(gb1 + ko, lwB1 + bo);
    }
    const int ro = (i % 3) * 4096;
    bf16x8 af[4], bf[4];
#pragma unroll
    for (int u = 0; u < 4; ++u) af[u] = *(const bf16x8*)(lrA + ro + u * 512);
#pragma unroll
    for (int u = 0; u < 4; ++u) bf[u] = *(const bf16x8*)(lrB + ro + u * 512);
#pragma unroll
    for (int ii = 0; ii < 4; ++ii)
#pragma unroll
      for (int jj = 0; jj < 4; ++jj)
        acc[ii][jj] = __builtin_amdgcn_mfma_f32_16x16x32_bf16(af[ii], bf[jj], acc[ii][jj], 0, 0, 0);
  }
}

// ---------------- fused TN GEMM: 128x128, 4 waves, pipelined ----------------
template <int MODE>
__global__ __launch_bounds__(256, 2) void gemm_tn_kernel(
    const unsigned short* __restrict__ Xb, const unsigned short* __restrict__ He,
    const unsigned short* __restrict__ Hs, const unsigned short* __restrict__ Wgu,
    const unsigned short* __restrict__ Sgu, const unsigned short* __restrict__ Wd,
    const unsigned short* __restrict__ Sd, unsigned short* __restrict__ HeOut,
    unsigned short* __restrict__ HsOut, float* __restrict__ De, float* __restrict__ Ds,
    const int* __restrict__ list, const int* __restrict__ counts,
    const int* __restrict__ offs) {
  const int ez = blockIdx.z;
  int cnt, lda, K;
  const unsigned short* A;
  const unsigned short* B;
  const int* alist = nullptr;
  unsigned short* H = nullptr;
  float* D = nullptr;
  int ldh = 0;

  if (MODE == 0) {
    if (ez < 8) {
      if (blockIdx.y >= 8) return;
      cnt = counts[ez]; A = Xb; alist = list + offs[ez]; lda = 1024; K = 1024;
      B = Wgu + (size_t)ez * 1024 * 1024; H = HeOut + (size_t)offs[ez] * 512; ldh = 512;
    } else {
      cnt = 2048; A = Xb; lda = 1024; K = 1024; B = Sgu; H = HsOut; ldh = 1024;
    }
  } else {
    if (ez < 8) {
      cnt = counts[ez]; A = He + (size_t)offs[ez] * 512; lda = 512; K = 512;
      B = Wd + (size_t)ez * 1024 * 512; D = De + (size_t)offs[ez] * 1024;
    } else {
      cnt = 2048; A = Hs; lda = 1024; K = 1024; B = Sd; D = Ds;
    }
  }

  const int m0 = blockIdx.x * 128;
  if (m0 >= cnt) return;
  const int n0 = blockIdx.y * 128;

  __shared__ unsigned short As[3 * 4096];   // 3 x 8 KB
  __shared__ unsigned short Bs[3 * 4096];   // 3 x 8 KB

  const int tid = threadIdx.x;
  const int srow = tid >> 2;
  const int scol = (tid & 3) * 8;
  const int wuni = (tid >> 6) * 512;

  int r0 = m0 + srow; if (r0 >= cnt) r0 = cnt - 1;
  int r1 = m0 + srow + 64; if (r1 >= cnt) r1 = cnt - 1;
  size_t abase0, abase1;
  if (MODE == 0 && ez < 8) {
    abase0 = (size_t)alist[r0] * lda; abase1 = (size_t)alist[r1] * lda;
  } else {
    abase0 = (size_t)r0 * lda; abase1 = (size_t)r1 * lda;
  }

  const unsigned short* ga0 = A + abase0 + scol;
  const unsigned short* ga1 = A + abase1 + scol;
  const unsigned short* gb0 = B + (size_t)(n0 + srow) * K + scol;
  const unsigned short* gb1 = B + (size_t)(n0 + srow + 64) * K + scol;

  unsigned short* lwA0 = As + wuni;
  unsigned short* lwA1 = As + 2048 + wuni;
  unsigned short* lwB0 = Bs + wuni;
  unsigned short* lwB1 = Bs + 2048 + wuni;

  const int wave = tid >> 6;
  const int lane = tid & 63;
  const int wm = (wave & 1) * 64;
  const int wn = (wave >> 1) * 64;
  const int fl = lane & 15;
  const int q = lane >> 4;

  const unsigned short* lrA = As + (wm + fl) * 32 + q * 8;
  const unsigned short* lrB = Bs + (wn + fl) * 32 + q * 8;

  f32x4 acc[4][4];
  f32x4 zero = {0.f, 0.f, 0.f, 0.f};
#pragma unroll
  for (int i = 0; i < 4; i++)
#pragma unroll
    for (int j = 0; j < 4; j++) acc[i][j] = zero;

  if (MODE == 1 && ez < 8) kloop<16>(ga0, ga1, gb0, gb1, lwA0, lwA1, lwB0, lwB1, lrA, lrB, acc);
  else                     kloop<32>(ga0, ga1, gb0, gb1, lwA0, lwA1, lwB0, lwB1, lrA, lrB, acc);

  if (MODE == 0) {
#pragma unroll
    for (int i = 0; i < 4; i++) {
#pragma unroll
      for (int j = 0; j < 4; j++) {
#pragma unroll
        for (int r = 0; r < 4; r++) {
          int grow = m0 + wm + i * 16 + q * 4 + r;
          float v = acc[i][j][r];
          float pv = __shfl_xor(v, 1);
          if ((lane & 1) == 0 && grow < cnt) {
            float s = v / (1.f + __expf(-v));
            int colh = (n0 + wn + j * 16 + fl) >> 1;
            H[(size_t)grow * ldh + colh] = f2bf(s * pv);
          }
        }
      }
    }
  } else {
#pragma unroll
    for (int i = 0; i < 4; i++) {
#pragma unroll
      for (int r = 0; r < 4; r++) {
        int grow = m0 + wm + i * 16 + q * 4 + r;
        if (grow >= cnt) continue;
#pragma unroll
        for (int j = 0; j < 4; j++) {
          int col = n0 + wn + j * 16 + fl;
          D[(size_t)grow * 1024 + col] = acc[i][j][r];
        }
      }
    }
  }
}

// ---------------- combine ----------------
__global__ __launch_bounds__(256) void combine_kernel(
    const float* __restrict__ Ds, const float* __restrict__ De,
    const int* __restrict__ ridx, const float* __restrict__ rp,
    float* __restrict__ out) {
  const int t = blockIdx.x;
  const int i0 = ridx[t * 2], i1 = ridx[t * 2 + 1];
  const float p0 = rp[t * 2], p1 = rp[t * 2 + 1];
  const float4* a  = (const float4*)(Ds + (size_t)t * 1024);
  const float4* b0 = (const float4*)(De + (size_t)i0 * 1024);
  const float4* b1 = (const float4*)(De + (size_t)i1 * 1024);
  float4* o = (float4*)(out + (size_t)t * 1024);
  int c = threadIdx.x;
  float4 va = a[c], v0 = b0[c], v1 = b1[c];
  float4 r;
  r.x = va.x + p0 * v0.x + p1 * v1.x;
  r.y = va.y + p0 * v0.y + p1 * v1.y;
  r.z = va.z + p0 * v0.z + p1 * v1.z;
  r.w = va.w + p0 * v0.w + p1 * v1.w;
  o[c] = r;
}

// ---------------- launch ----------------
extern "C" void kernel_launch(void* const* d_in, const int* in_sizes, int n_in,
                              void* d_out, int out_size, void* d_ws, size_t ws_size,
                              hipStream_t stream) {
  const float* x    = (const float*)d_in[0];
  const float* Wr   = (const float*)d_in[1];
  const float* Wg   = (const float*)d_in[2];
  const float* Wu   = (const float*)d_in[3];
  const float* Wd   = (const float*)d_in[4];
  const float* Sg   = (const float*)d_in[5];
  const float* Su   = (const float*)d_in[6];
  const float* Sd   = (const float*)d_in[7];
  const float* bias = (const float*)d_in[8];
  float* out = (float*)d_out;

  char* ws = (char*)d_ws;
  size_t o = 0;
  auto alloc = [&](size_t b) { char* p = ws + o; o += (b + 255) & ~(size_t)255; return p; };
  unsigned short* Xb   = (unsigned short*)alloc((size_t)2048 * 1024 * 2);
  unsigned short* WguT = (unsigned short*)alloc((size_t)8 * 1024 * 1024 * 2);
  unsigned short* WdT  = (unsigned short*)alloc((size_t)8 * 1024 * 512 * 2);
  unsigned short* SguT = (unsigned short*)alloc((size_t)2048 * 1024 * 2);
  unsigned short* SdT  = (unsigned short*)alloc((size_t)1024 * 1024 * 2);
  float* logits = (float*)alloc((size_t)2048 * 8 * 4);
  int*   list   = (int*)alloc((size_t)4096 * 4);
  int*   ridx   = (int*)alloc((size_t)2048 * 2 * 4);
  float* rp     = (float*)alloc((size_t)2048 * 2 * 4);
  int*   counts = (int*)alloc(64);
  int*   offs   = (int*)alloc(64);
  unsigned short* He = (unsigned short*)alloc((size_t)4096 * 512 * 2);
  unsigned short* Hs = (unsigned short*)alloc((size_t)2048 * 1024 * 2);
  float* De = (float*)alloc((size_t)4096 * 1024 * 4);
  float* Ds = (float*)alloc((size_t)2048 * 1024 * 4);

  cvt_bf16_kernel<<<2048, 256, 0, stream>>>(x, Xb, 2048 * 1024);
  transpose_cvt_all<<<dim3(16, 16, 27), 256, 0, stream>>>(Wg, Wu, Wd, Sg, Su, Sd,
                                                          WguT, WdT, SguT, SdT);

  logits_kernel<<<512, 256, 0, stream>>>(x, Wr, logits);
  assign_kernel<<<1, 1024, 0, stream>>>(logits, bias, list, ridx, rp, counts, offs);

  gemm_tn_kernel<0><<<dim3(16, 16, 9), 256, 0, stream>>>(
      Xb, He, Hs, WguT, SguT, WdT, SdT, He, Hs, De, Ds, list, counts, offs);
  gemm_tn_kernel<1><<<dim3(16, 8, 9), 256, 0, stream>>>(
      Xb, He, Hs, WguT, SguT, WdT, SdT, He, Hs, De, Ds, list, counts, offs);

  combine_kernel<<<2048, 256, 0, stream>>>(Ds, De, ridx, rp, out);
}

// Round 9
// 200.831 us; speedup vs baseline: 1.3289x; 1.1913x over previous
//
#include <hip/hip_runtime.h>
#include <cstdint>
#include <cstddef>

typedef __attribute__((ext_vector_type(8))) short bf16x8;
typedef __attribute__((ext_vector_type(4))) float f32x4;
typedef __attribute__((ext_vector_type(4))) unsigned short u16x4;

#define AS1 __attribute__((address_space(1)))
#define AS3 __attribute__((address_space(3)))

__device__ __forceinline__ unsigned short f2bf(float f) {
  union { float f; unsigned int u; } v; v.f = f;
  unsigned int r = v.u + 0x7fffu + ((v.u >> 16) & 1u);
  return (unsigned short)(r >> 16);
}

__device__ __forceinline__ void gll16(const unsigned short* g, unsigned short* l) {
  __builtin_amdgcn_global_load_lds((const AS1 void*)g, (AS3 void*)l, 16, 0, 0);
}

// ---------------- weight transposes + x cast, one dispatch ----------------
// z 0..7:  Wg[e] 1024x512 -> WguT[e] even rows (drp 2048)
// z 8..15: Wu[e] -> WguT odd rows;  z 16..23: Wd[e] 512x1024 -> WdT[e] (drp 512)
// z 24: Sg->SguT even; 25: Su->SguT odd; 26: Sd->SdT; 27..30: x -> Xb cast copy
__global__ __launch_bounds__(256) void transpose_cvt_all(
    const float* __restrict__ Wg, const float* __restrict__ Wu,
    const float* __restrict__ Wd, const float* __restrict__ Sg,
    const float* __restrict__ Su, const float* __restrict__ Sd,
    const float* __restrict__ x,
    unsigned short* __restrict__ WguT, unsigned short* __restrict__ WdT,
    unsigned short* __restrict__ SguT, unsigned short* __restrict__ SdT,
    unsigned short* __restrict__ Xb) {
  const int z = blockIdx.z;
  const int tid = threadIdx.x;

  if (z >= 27) {  // ---- copy-cast x ----
    size_t off = (size_t)(z - 27) * 524288 + blockIdx.y * 32768 + blockIdx.x * 2048 + tid * 8;
    const float4* s = (const float4*)(x + off);
    float4 a = s[0], b = s[1];
    bf16x8 o = { (short)f2bf(a.x), (short)f2bf(a.y), (short)f2bf(a.z), (short)f2bf(a.w),
                 (short)f2bf(b.x), (short)f2bf(b.y), (short)f2bf(b.z), (short)f2bf(b.w) };
    *(bf16x8*)(Xb + off) = o;
    return;
  }

  const float* src; unsigned short* dst; int R, C, drp;
  if (z < 8)       { src = Wg + (size_t)z * 524288; dst = WguT + (size_t)z * 1048576; R = 1024; C = 512; drp = 2048; }
  else if (z < 16) { src = Wu + (size_t)(z - 8) * 524288; dst = WguT + (size_t)(z - 8) * 1048576 + 1024; R = 1024; C = 512; drp = 2048; }
  else if (z < 24) { src = Wd + (size_t)(z - 16) * 524288; dst = WdT + (size_t)(z - 16) * 524288; R = 512; C = 1024; drp = 512; }
  else if (z == 24){ src = Sg; dst = SguT; R = 1024; C = 1024; drp = 2048; }
  else if (z == 25){ src = Su; dst = SguT + 1024; R = 1024; C = 1024; drp = 2048; }
  else             { src = Sd; dst = SdT; R = 1024; C = 1024; drp = 1024; }
  const int c0 = blockIdx.x * 64, r0 = blockIdx.y * 64;
  if (c0 >= C || r0 >= R) return;

  __shared__ float tile[64][65];
  {
    // read 64x64 tile: thread -> row tid>>2, 16 cols at (tid&3)*16, float4 x4
    const int row = tid >> 2, cs = (tid & 3) * 16;
    const float* sp = src + (size_t)(r0 + row) * C + c0 + cs;
#pragma unroll
    for (int k = 0; k < 4; k++) {
      float4 v = ((const float4*)sp)[k];
      tile[row][cs + k * 4 + 0] = v.x; tile[row][cs + k * 4 + 1] = v.y;
      tile[row][cs + k * 4 + 2] = v.z; tile[row][cs + k * 4 + 3] = v.w;
    }
  }
  __syncthreads();
  // write transposed: thread -> col cc = i*32 + (tid>>3), rows rseg=(tid&7)*8, bf16x8
#pragma unroll
  for (int i = 0; i < 2; i++) {
    const int cc = i * 32 + (tid >> 3);
    const int rseg = (tid & 7) * 8;
    bf16x8 o;
#pragma unroll
    for (int j = 0; j < 8; j++) o[j] = (short)f2bf(tile[rseg + j][cc]);
    *(bf16x8*)(dst + (size_t)(c0 + cc) * drp + r0 + rseg) = o;
  }
}

// ---------------- router: logits ----------------
__global__ __launch_bounds__(256) void logits_kernel(const float* __restrict__ x,
                                                     const float* __restrict__ Wr,
                                                     float* __restrict__ logits) {
  const int t = blockIdx.x * 4 + (threadIdx.x >> 6);
  const int lane = threadIdx.x & 63;
  const float* xr = x + (size_t)t * 1024;
  float acc[8];
#pragma unroll
  for (int e = 0; e < 8; e++) acc[e] = 0.f;
#pragma unroll
  for (int i = 0; i < 16; i++) {
    int d = lane + i * 64;
    float xv = xr[d];
    const float4* w = (const float4*)(Wr + d * 8);
    float4 w0 = w[0], w1 = w[1];
    acc[0] += xv * w0.x; acc[1] += xv * w0.y; acc[2] += xv * w0.z; acc[3] += xv * w0.w;
    acc[4] += xv * w1.x; acc[5] += xv * w1.y; acc[6] += xv * w1.z; acc[7] += xv * w1.w;
  }
#pragma unroll
  for (int off = 32; off > 0; off >>= 1)
#pragma unroll
    for (int e = 0; e < 8; e++) acc[e] += __shfl_down(acc[e], off);
  if (lane == 0) {
#pragma unroll
    for (int e = 0; e < 8; e++) logits[t * 8 + e] = acc[e];
  }
}

// ---------------- router: assignment ----------------
__global__ __launch_bounds__(1024) void assign_kernel(
    const float* __restrict__ logits, const float* __restrict__ bias,
    int* __restrict__ list, int* __restrict__ ridx, float* __restrict__ rp,
    int* __restrict__ counts_g, int* __restrict__ offs_g) {
  __shared__ int cnt[8];
  __shared__ int offs[9];
  const int tid = threadIdx.x;
  if (tid < 8) cnt[tid] = 0;
  __syncthreads();
  int te[2][2], tpos[2][2];
  float tp[2][2];
#pragma unroll
  for (int it = 0; it < 2; it++) {
    int t = tid + it * 1024;
    float v[8];
#pragma unroll
    for (int e = 0; e < 8; e++) v[e] = logits[t * 8 + e] + bias[e];
    int i0 = 0;
#pragma unroll
    for (int e = 1; e < 8; e++) if (v[e] > v[i0]) i0 = e;
    int i1 = (i0 == 0) ? 1 : 0;
#pragma unroll
    for (int e = 0; e < 8; e++) if (e != i0 && v[e] > v[i1]) i1 = e;
    float pa = 1.f / (1.f + __expf(v[i1] - v[i0]));
    te[it][0] = i0; te[it][1] = i1;
    tp[it][0] = pa; tp[it][1] = 1.f - pa;
    tpos[it][0] = atomicAdd(&cnt[i0], 1);
    tpos[it][1] = atomicAdd(&cnt[i1], 1);
  }
  __syncthreads();
  if (tid == 0) {
    int s = 0;
#pragma unroll
    for (int e = 0; e < 8; e++) { offs[e] = s; s += cnt[e]; }
    offs[8] = s;
#pragma unroll
    for (int e = 0; e < 8; e++) { counts_g[e] = cnt[e]; offs_g[e] = offs[e]; }
    offs_g[8] = s;
  }
  __syncthreads();
#pragma unroll
  for (int it = 0; it < 2; it++) {
    int t = tid + it * 1024;
#pragma unroll
    for (int k = 0; k < 2; k++) {
      int grow = offs[te[it][k]] + tpos[it][k];
      list[grow] = t;
      ridx[t * 2 + k] = grow;
      rp[t * 2 + k] = tp[it][k];
    }
  }
}

// ---------------- pipelined K-loop (3 LDS buffers, vmcnt(4) across raw barrier) ----------------
template <int NK>
__device__ __forceinline__ void kloop(
    const unsigned short* ga0, const unsigned short* ga1,
    const unsigned short* gb0, const unsigned short* gb1,
    unsigned short* lwA0, unsigned short* lwA1,
    unsigned short* lwB0, unsigned short* lwB1,
    const unsigned short* lrA, const unsigned short* lrB,
    f32x4 (&acc)[4][4]) {
  gll16(ga0, lwA0);          gll16(ga1, lwA1);
  gll16(gb0, lwB0);          gll16(gb1, lwB1);
  gll16(ga0 + 32, lwA0 + 4096); gll16(ga1 + 32, lwA1 + 4096);
  gll16(gb0 + 32, lwB0 + 4096); gll16(gb1 + 32, lwB1 + 4096);
#pragma unroll
  for (int i = 0; i < NK; ++i) {
    if (i + 1 < NK) asm volatile("s_waitcnt vmcnt(4) lgkmcnt(0)\n\ts_barrier" ::: "memory");
    else            asm volatile("s_waitcnt vmcnt(0) lgkmcnt(0)\n\ts_barrier" ::: "memory");
    if (i + 2 < NK) {
      const int bo = ((i + 2) % 3) * 4096;
      const int ko = (i + 2) * 32;
      gll16(ga0 + ko, lwA0 + bo); gll16(ga1 + ko, lwA1 + bo);
      gll16(gb0 + ko, lwB0 + bo); gll16(gb1 + ko, lwB1 + bo);
    }
    const int ro = (i % 3) * 4096;
    bf16x8 af[4], bf[4];
#pragma unroll
    for (int u = 0; u < 4; ++u) af[u] = *(const bf16x8*)(lrA + ro + u * 512);
#pragma unroll
    for (int u = 0; u < 4; ++u) bf[u] = *(const bf16x8*)(lrB + ro + u * 512);
#pragma unroll
    for (int ii = 0; ii < 4; ++ii)
#pragma unroll
      for (int jj = 0; jj < 4; ++jj)
        acc[ii][jj] = __builtin_amdgcn_mfma_f32_16x16x32_bf16(af[ii], bf[jj], acc[ii][jj], 0, 0, 0);
  }
}

// ---------------- fused TN GEMM: 128x128, 4 waves, pipelined, interleaved dispatch ----------------
// ez = blockIdx.x (FASTEST dim) -> consecutive blocks cycle expert 0..7, shared;
// routed and shared phases co-resident, ~3 blocks/CU.
template <int MODE>
__global__ __launch_bounds__(256, 3) void gemm_tn_kernel(
    const unsigned short* __restrict__ Xb, const unsigned short* __restrict__ He,
    const unsigned short* __restrict__ Hs, const unsigned short* __restrict__ Wgu,
    const unsigned short* __restrict__ Sgu, const unsigned short* __restrict__ Wd,
    const unsigned short* __restrict__ Sd, unsigned short* __restrict__ HeOut,
    unsigned short* __restrict__ HsOut, float* __restrict__ De, float* __restrict__ Ds,
    const int* __restrict__ list, const int* __restrict__ counts,
    const int* __restrict__ offs) {
  const int ez = blockIdx.x;
  int cnt, lda, K;
  const unsigned short* A;
  const unsigned short* B;
  const int* alist = nullptr;
  unsigned short* H = nullptr;
  float* D = nullptr;
  int ldh = 0;

  if (MODE == 0) {
    if (ez < 8) {
      if (blockIdx.z >= 8) return;   // routed N = 1024 -> 8 n-tiles
      cnt = counts[ez]; A = Xb; alist = list + offs[ez]; lda = 1024; K = 1024;
      B = Wgu + (size_t)ez * 1024 * 1024; H = HeOut + (size_t)offs[ez] * 512; ldh = 512;
    } else {
      cnt = 2048; A = Xb; lda = 1024; K = 1024; B = Sgu; H = HsOut; ldh = 1024;
    }
  } else {
    if (ez < 8) {
      cnt = counts[ez]; A = He + (size_t)offs[ez] * 512; lda = 512; K = 512;
      B = Wd + (size_t)ez * 1024 * 512; D = De + (size_t)offs[ez] * 1024;
    } else {
      cnt = 2048; A = Hs; lda = 1024; K = 1024; B = Sd; D = Ds;
    }
  }

  const int m0 = blockIdx.y * 128;
  if (m0 >= cnt) return;
  const int n0 = blockIdx.z * 128;

  __shared__ unsigned short As[3 * 4096];   // 3 x 8 KB
  __shared__ unsigned short Bs[3 * 4096];   // 3 x 8 KB

  const int tid = threadIdx.x;
  const int srow = tid >> 2;
  const int scol = (tid & 3) * 8;
  const int wuni = (tid >> 6) * 512;

  int r0 = m0 + srow; if (r0 >= cnt) r0 = cnt - 1;
  int r1 = m0 + srow + 64; if (r1 >= cnt) r1 = cnt - 1;
  size_t abase0, abase1;
  if (MODE == 0 && ez < 8) {
    abase0 = (size_t)alist[r0] * lda; abase1 = (size_t)alist[r1] * lda;
  } else {
    abase0 = (size_t)r0 * lda; abase1 = (size_t)r1 * lda;
  }

  const unsigned short* ga0 = A + abase0 + scol;
  const unsigned short* ga1 = A + abase1 + scol;
  const unsigned short* gb0 = B + (size_t)(n0 + srow) * K + scol;
  const unsigned short* gb1 = B + (size_t)(n0 + srow + 64) * K + scol;

  unsigned short* lwA0 = As + wuni;
  unsigned short* lwA1 = As + 2048 + wuni;
  unsigned short* lwB0 = Bs + wuni;
  unsigned short* lwB1 = Bs + 2048 + wuni;

  const int wave = tid >> 6;
  const int lane = tid & 63;
  const int wm = (wave & 1) * 64;
  const int wn = (wave >> 1) * 64;
  const int fl = lane & 15;
  const int q = lane >> 4;

  const unsigned short* lrA = As + (wm + fl) * 32 + q * 8;
  const unsigned short* lrB = Bs + (wn + fl) * 32 + q * 8;

  f32x4 acc[4][4];
  f32x4 zero = {0.f, 0.f, 0.f, 0.f};
#pragma unroll
  for (int i = 0; i < 4; i++)
#pragma unroll
    for (int j = 0; j < 4; j++) acc[i][j] = zero;

  if (MODE == 1 && ez < 8) kloop<16>(ga0, ga1, gb0, gb1, lwA0, lwA1, lwB0, lwB1, lrA, lrB, acc);
  else                     kloop<32>(ga0, ga1, gb0, gb1, lwA0, lwA1, lwB0, lwB1, lrA, lrB, acc);

  if (MODE == 0) {
#pragma unroll
    for (int i = 0; i < 4; i++) {
#pragma unroll
      for (int j = 0; j < 4; j++) {
#pragma unroll
        for (int r = 0; r < 4; r++) {
          int grow = m0 + wm + i * 16 + q * 4 + r;
          float v = acc[i][j][r];
          float pv = __shfl_xor(v, 1);
          if ((lane & 1) == 0 && grow < cnt) {
            float s = v / (1.f + __expf(-v));
            int colh = (n0 + wn + j * 16 + fl) >> 1;
            H[(size_t)grow * ldh + colh] = f2bf(s * pv);
          }
        }
      }
    }
  } else {
#pragma unroll
    for (int i = 0; i < 4; i++) {
#pragma unroll
      for (int r = 0; r < 4; r++) {
        int grow = m0 + wm + i * 16 + q * 4 + r;
        if (grow >= cnt) continue;
#pragma unroll
        for (int j = 0; j < 4; j++) {
          int col = n0 + wn + j * 16 + fl;
          D[(size_t)grow * 1024 + col] = acc[i][j][r];
        }
      }
    }
  }
}

// ---------------- combine ----------------
__global__ __launch_bounds__(256) void combine_kernel(
    const float* __restrict__ Ds, const float* __restrict__ De,
    const int* __restrict__ ridx, const float* __restrict__ rp,
    float* __restrict__ out) {
  const int t = blockIdx.x;
  const int i0 = ridx[t * 2], i1 = ridx[t * 2 + 1];
  const float p0 = rp[t * 2], p1 = rp[t * 2 + 1];
  const float4* a  = (const float4*)(Ds + (size_t)t * 1024);
  const float4* b0 = (const float4*)(De + (size_t)i0 * 1024);
  const float4* b1 = (const float4*)(De + (size_t)i1 * 1024);
  float4* o = (float4*)(out + (size_t)t * 1024);
  int c = threadIdx.x;
  float4 va = a[c], v0 = b0[c], v1 = b1[c];
  float4 r;
  r.x = va.x + p0 * v0.x + p1 * v1.x;
  r.y = va.y + p0 * v0.y + p1 * v1.y;
  r.z = va.z + p0 * v0.z + p1 * v1.z;
  r.w = va.w + p0 * v0.w + p1 * v1.w;
  o[c] = r;
}

// ---------------- launch ----------------
extern "C" void kernel_launch(void* const* d_in, const int* in_sizes, int n_in,
                              void* d_out, int out_size, void* d_ws, size_t ws_size,
                              hipStream_t stream) {
  const float* x    = (const float*)d_in[0];
  const float* Wr   = (const float*)d_in[1];
  const float* Wg   = (const float*)d_in[2];
  const float* Wu   = (const float*)d_in[3];
  const float* Wd   = (const float*)d_in[4];
  const float* Sg   = (const float*)d_in[5];
  const float* Su   = (const float*)d_in[6];
  const float* Sd   = (const float*)d_in[7];
  const float* bias = (const float*)d_in[8];
  float* out = (float*)d_out;

  char* ws = (char*)d_ws;
  size_t o = 0;
  auto alloc = [&](size_t b) { char* p = ws + o; o += (b + 255) & ~(size_t)255; return p; };
  unsigned short* Xb   = (unsigned short*)alloc((size_t)2048 * 1024 * 2);
  unsigned short* WguT = (unsigned short*)alloc((size_t)8 * 1024 * 1024 * 2);
  unsigned short* WdT  = (unsigned short*)alloc((size_t)8 * 1024 * 512 * 2);
  unsigned short* SguT = (unsigned short*)alloc((size_t)2048 * 1024 * 2);
  unsigned short* SdT  = (unsigned short*)alloc((size_t)1024 * 1024 * 2);
  float* logits = (float*)alloc((size_t)2048 * 8 * 4);
  int*   list   = (int*)alloc((size_t)4096 * 4);
  int*   ridx   = (int*)alloc((size_t)2048 * 2 * 4);
  float* rp     = (float*)alloc((size_t)2048 * 2 * 4);
  int*   counts = (int*)alloc(64);
  int*   offs   = (int*)alloc(64);
  unsigned short* He = (unsigned short*)alloc((size_t)4096 * 512 * 2);
  unsigned short* Hs = (unsigned short*)alloc((size_t)2048 * 1024 * 2);
  float* De = (float*)alloc((size_t)4096 * 1024 * 4);
  float* Ds = (float*)alloc((size_t)2048 * 1024 * 4);

  transpose_cvt_all<<<dim3(16, 16, 31), 256, 0, stream>>>(Wg, Wu, Wd, Sg, Su, Sd, x,
                                                          WguT, WdT, SguT, SdT, Xb);

  logits_kernel<<<512, 256, 0, stream>>>(x, Wr, logits);
  assign_kernel<<<1, 1024, 0, stream>>>(logits, bias, list, ridx, rp, counts, offs);

  gemm_tn_kernel<0><<<dim3(9, 16, 16), 256, 0, stream>>>(
      Xb, He, Hs, WguT, SguT, WdT, SdT, He, Hs, De, Ds, list, counts, offs);
  gemm_tn_kernel<1><<<dim3(9, 16, 8), 256, 0, stream>>>(
      Xb, He, Hs, WguT, SguT, WdT, SdT, He, Hs, De, Ds, list, counts, offs);

  combine_kernel<<<2048, 256, 0, stream>>>(Ds, De, ridx, rp, out);
}